// Round 1
// baseline (244.514 us; speedup 1.0000x reference)
//
#include <hip/hip_runtime.h>
#include <cstdint>
#include <cstddef>

#define DEVI __device__ __forceinline__

typedef short    shortx8 __attribute__((ext_vector_type(8)));
typedef short    shortx4 __attribute__((ext_vector_type(4)));
typedef short    shortx2 __attribute__((ext_vector_type(2)));
typedef __bf16   bf16x8  __attribute__((ext_vector_type(8)));
typedef float    floatx4 __attribute__((ext_vector_type(4)));

DEVI unsigned short f2b(float f) {
    union { float f; unsigned u; } a; a.f = f;
    unsigned r = a.u + 0x7fffu + ((a.u >> 16) & 1u);
    return (unsigned short)(r >> 16);
}
DEVI float b2f(unsigned short u) {
    union { unsigned u; float f; } a; a.u = ((unsigned)u) << 16;
    return a.f;
}

DEVI floatx4 mfma_bf16(bf16x8 a, bf16x8 b, floatx4 c) {
    return __builtin_amdgcn_mfma_f32_16x16x32_bf16(a, b, c, 0, 0, 0);
}

DEVI void glds16(const ushort* g, ushort* l) {
    __builtin_amdgcn_global_load_lds(
        (const __attribute__((address_space(1))) void*)g,
        (__attribute__((address_space(3))) void*)l, 16, 0, 0);
}

// barrier + compiler-level memory fence (prevents IR/MIR motion of LDS ops
// across the barrier; runtime cost zero for the empty asm)
DEVI void barrier_f() {
    __builtin_amdgcn_s_barrier();
    asm volatile("" ::: "memory");
}

template <bool B> struct BoolT { static constexpr bool value = B; };

// ---------------- fused prep: x->bf16, W transposes, bias pack ----------------
__global__ void k_prep(const float* __restrict__ x, ushort* __restrict__ xb,
                       const float* __restrict__ Wq, const float* __restrict__ Wk,
                       const float* __restrict__ Wv, const float* __restrict__ Wo,
                       ushort* __restrict__ Wt, ushort* __restrict__ Wot,
                       const float* __restrict__ bq, const float* __restrict__ bk,
                       const float* __restrict__ bv, float* __restrict__ bqkv) {
    __shared__ float tile[64][65];
    const int bid = blockIdx.x, t = threadIdx.x;
    if (bid < 6144) {                      // x -> bf16
        size_t i = ((size_t)bid * 256 + t) * 8;
        float4 v0 = *(const float4*)(x + i);
        float4 v1 = *(const float4*)(x + i + 4);
        shortx8 o;
        o[0] = (short)f2b(v0.x); o[1] = (short)f2b(v0.y);
        o[2] = (short)f2b(v0.z); o[3] = (short)f2b(v0.w);
        o[4] = (short)f2b(v1.x); o[5] = (short)f2b(v1.y);
        o[6] = (short)f2b(v1.z); o[7] = (short)f2b(v1.w);
        *(shortx8*)(xb + i) = o;
    } else if (bid < 6720) {               // W [in][out] fp32 -> [out][in] bf16
        int pid = bid - 6144;
        int zi = pid / 144, rem = pid % 144;
        const float* W = (zi == 0) ? Wq : (zi == 1) ? Wk : (zi == 2) ? Wv : Wo;
        const int i0 = (rem / 12) * 64, j0 = (rem % 12) * 64;
        const int c = t & 63, r4 = t >> 6;
        for (int rr = r4; rr < 64; rr += 4)
            tile[rr][c] = W[(size_t)(i0 + rr) * 768 + j0 + c];
        __syncthreads();
        ushort* dst = (zi < 3) ? (Wt + (size_t)(zi * 768) * 768) : Wot;
        for (int jj = r4; jj < 64; jj += 4)
            dst[(size_t)(j0 + jj) * 768 + i0 + c] = f2b(tile[c][jj]);
    } else {                               // bias pack
        int j = (bid - 6720) * 256 + t;
        if (j < 2304) {
            const float* src = (j < 768) ? bq : (j < 1536) ? bk : bv;
            bqkv[j] = src[j % 768];
        }
    }
}

// ---------------- main GEMM: 256x256 tile, BK=64, 8-phase counted-vmcnt ------
// Schedule (learn_hip m201 template, T2+T3+T4+T5):
//   8 waves as 2M x 4N; per-wave output 128x64 = acc[8][4] 16x16 fragments.
//   LDS: 2 buffers x (A 256x64 + B 256x64) bf16 = 128 KiB.
//   Per K-tile kt: 4 phases, each = {ds_read frag subtile; issue one prefetch
//   unit of kt+1 (2 x glds16); barrier; lgkmcnt(0); setprio(1); 16 MFMA;
//   setprio(0); vmcnt(4); barrier}.
//   Prefetch units in issue order:  U0A (A rows 0-63,128-191)  -> read at ph0
//                                   U0B (B ns0 rows)           -> read at ph0
//                                   U1  (B ns1 rows)           -> read at ph1
//                                   U2  (A rows 64-127,192-255)-> read at ph2
//   Uniform vmcnt(4) at each phase end leaves exactly the last 2 phases'
//   loads in flight => the unit needed next phase is always complete, and
//   the pipe never drains to 0 in the main loop. Epilogue drains 4->2->0.
// LDS swizzle (unchanged from previous version, conflict-free, glds-compatible):
//   element (r,k) at r*64 + ((k>>3)^(r&7))*8 + (k&7); staging pre-swizzles the
//   per-lane GLOBAL column (lc) so the LDS destination stays lane-linear.
template <int MODE>
__global__ __launch_bounds__(512, 2) void k_gemm(
    const ushort* __restrict__ A, const ushort* __restrict__ Bt,
    const float* __restrict__ bias, void* __restrict__ Cout, int Ncols) {
    constexpr int K = 768;
    constexpr int NKT = K / 64;            // 12 K-tiles
    __shared__ ushort As[2][256 * 64];
    __shared__ ushort Bs[2][256 * 64];
    const int m0 = blockIdx.x * 256;
    const int n0 = blockIdx.y * 256;
    const int tid = threadIdx.x;
    const int w = tid >> 6, lane = tid & 63;
    const int wm = w >> 2, wn = w & 3;     // wave -> (M-half, N-quarter)
    const int lr = lane >> 3, ls = lane & 7;
    const int lc = (ls ^ lr) * 8;          // swizzled source chunk
    const int fr = lane & 15, q4 = lane >> 4;

    // per-thread global staging bases (A: wave stages 8-row slabs at w*8;
    // B: wave stages 8-row slabs at (w>>2)*64 + (w&3)*8)
    const ushort* gA = A  + (size_t)(m0 + w * 8 + lr) * K + lc;
    const ushort* gB = Bt + (size_t)(n0 + (w >> 2) * 64 + (w & 3) * 8 + lr) * K + lc;
    const int aOfs = (w * 8) * 64;                                // wave-uniform
    const int bOfs = ((w >> 2) * 64 + (w & 3) * 8) * 64;          // wave-uniform

    floatx4 acc[8][4] = {};

    // -------- prologue: stage K-tile 0 into buffer 0 (steady-state order) ----
    glds16(gA,           As[0] + aOfs);
    glds16(gA + 128 * K, As[0] + 128 * 64 + aOfs);
    glds16(gB,           Bs[0] + bOfs);
    glds16(gB + 128 * K, Bs[0] + 128 * 64 + bOfs);
    glds16(gB + 32 * K,  Bs[0] + 32 * 64 + bOfs);
    glds16(gB + 160 * K, Bs[0] + 160 * 64 + bOfs);
    glds16(gA + 64 * K,  As[0] + 64 * 64 + aOfs);
    glds16(gA + 192 * K, As[0] + 192 * 64 + aOfs);
    asm volatile("s_waitcnt vmcnt(4)" ::: "memory");   // U0A+U0B landed
    barrier_f();

    auto tile = [&](int kt, auto stc) {
        constexpr bool ST = decltype(stc)::value;      // stage next tile?
        const int cur = kt & 1;
        const ushort* a_ = As[cur];
        const ushort* b_ = Bs[cur];
        ushort* An = As[cur ^ 1];
        ushort* Bn = Bs[cur ^ 1];
        const int ko = (kt + 1) * 64;
        bf16x8 af[2][4], bfv[2][2][2];                 // [kc][rt], [ns][kc][nt]

        // ===================== phase 0: (ms=0, ns=0) =====================
#pragma unroll
        for (int kc = 0; kc < 2; ++kc) {
            const int off = ((kc * 4 + q4) ^ (fr & 7)) * 8;
#pragma unroll
            for (int rt = 0; rt < 4; ++rt)
                af[kc][rt] = *(const bf16x8*)(a_ + (wm * 128 + rt * 16 + fr) * 64 + off);
#pragma unroll
            for (int nt = 0; nt < 2; ++nt)
                bfv[0][kc][nt] = *(const bf16x8*)(b_ + (wn * 64 + nt * 16 + fr) * 64 + off);
        }
        if constexpr (ST) {                            // issue U0A of kt+1
            glds16(gA + ko,           An + aOfs);
            glds16(gA + 128 * K + ko, An + 128 * 64 + aOfs);
        }
        barrier_f();
        asm volatile("s_waitcnt lgkmcnt(0)" ::: "memory");
        __builtin_amdgcn_sched_barrier(0);
        __builtin_amdgcn_s_setprio(1);
#pragma unroll
        for (int kc = 0; kc < 2; ++kc)
#pragma unroll
            for (int rt = 0; rt < 4; ++rt)
#pragma unroll
                for (int nt = 0; nt < 2; ++nt)
                    acc[rt][nt] = mfma_bf16(af[kc][rt], bfv[0][kc][nt], acc[rt][nt]);
        __builtin_amdgcn_s_setprio(0);
        if constexpr (ST) asm volatile("s_waitcnt vmcnt(4)" ::: "memory");
        else              asm volatile("s_waitcnt vmcnt(2)" ::: "memory");
        barrier_f();

        // ===================== phase 1: (ms=0, ns=1) =====================
#pragma unroll
        for (int kc = 0; kc < 2; ++kc) {
            const int off = ((kc * 4 + q4) ^ (fr & 7)) * 8;
#pragma unroll
            for (int nt = 0; nt < 2; ++nt)
                bfv[1][kc][nt] = *(const bf16x8*)(b_ + (wn * 64 + 32 + nt * 16 + fr) * 64 + off);
        }
        if constexpr (ST) {                            // issue U0B of kt+1
            glds16(gB + ko,           Bn + bOfs);
            glds16(gB + 128 * K + ko, Bn + 128 * 64 + bOfs);
        }
        barrier_f();
        asm volatile("s_waitcnt lgkmcnt(0)" ::: "memory");
        __builtin_amdgcn_sched_barrier(0);
        __builtin_amdgcn_s_setprio(1);
#pragma unroll
        for (int kc = 0; kc < 2; ++kc)
#pragma unroll
            for (int rt = 0; rt < 4; ++rt)
#pragma unroll
                for (int nt = 0; nt < 2; ++nt)
                    acc[rt][2 + nt] = mfma_bf16(af[kc][rt], bfv[1][kc][nt], acc[rt][2 + nt]);
        __builtin_amdgcn_s_setprio(0);
        if constexpr (ST) asm volatile("s_waitcnt vmcnt(4)" ::: "memory");
        else              asm volatile("s_waitcnt vmcnt(0)" ::: "memory");
        barrier_f();

        // ===================== phase 2: (ms=1, ns=0) =====================
#pragma unroll
        for (int kc = 0; kc < 2; ++kc) {
            const int off = ((kc * 4 + q4) ^ (fr & 7)) * 8;
#pragma unroll
            for (int rt = 0; rt < 4; ++rt)
                af[kc][rt] = *(const bf16x8*)(a_ + (wm * 128 + 64 + rt * 16 + fr) * 64 + off);
        }
        if constexpr (ST) {                            // issue U1 of kt+1
            glds16(gB + 32 * K + ko,  Bn + 32 * 64 + bOfs);
            glds16(gB + 160 * K + ko, Bn + 160 * 64 + bOfs);
        }
        barrier_f();
        asm volatile("s_waitcnt lgkmcnt(0)" ::: "memory");
        __builtin_amdgcn_sched_barrier(0);
        __builtin_amdgcn_s_setprio(1);
#pragma unroll
        for (int kc = 0; kc < 2; ++kc)
#pragma unroll
            for (int rt = 0; rt < 4; ++rt)
#pragma unroll
                for (int nt = 0; nt < 2; ++nt)
                    acc[4 + rt][nt] = mfma_bf16(af[kc][rt], bfv[0][kc][nt], acc[4 + rt][nt]);
        __builtin_amdgcn_s_setprio(0);
        if constexpr (ST) {
            asm volatile("s_waitcnt vmcnt(4)" ::: "memory");
            barrier_f();
        }

        // ===================== phase 3: (ms=1, ns=1) =====================
        if constexpr (ST) {                            // issue U2 of kt+1
            glds16(gA + 64 * K + ko,  An + 64 * 64 + aOfs);
            glds16(gA + 192 * K + ko, An + 192 * 64 + aOfs);
            barrier_f();
        }
        __builtin_amdgcn_s_setprio(1);
#pragma unroll
        for (int kc = 0; kc < 2; ++kc)
#pragma unroll
            for (int rt = 0; rt < 4; ++rt)
#pragma unroll
                for (int nt = 0; nt < 2; ++nt)
                    acc[4 + rt][2 + nt] = mfma_bf16(af[kc][rt], bfv[1][kc][nt], acc[4 + rt][2 + nt]);
        __builtin_amdgcn_s_setprio(0);
        if constexpr (ST) {
            asm volatile("s_waitcnt vmcnt(4)" ::: "memory");
            barrier_f();
        }
    };

#pragma unroll 1
    for (int kt = 0; kt < NKT - 1; ++kt) tile(kt, BoolT<true>{});
    tile(NKT - 1, BoolT<false>{});

    // ------------------------------ epilogue ---------------------------------
    float bv[4];
#pragma unroll
    for (int ni = 0; ni < 4; ++ni) bv[ni] = bias[n0 + wn * 64 + ni * 16 + fr];
#pragma unroll
    for (int mi = 0; mi < 8; ++mi) {
#pragma unroll
        for (int ni = 0; ni < 4; ++ni) {
#pragma unroll
            for (int r = 0; r < 4; ++r) {
                const int m = m0 + wm * 128 + mi * 16 + q4 * 4 + r;
                const int n = n0 + wn * 64 + ni * 16 + fr;
                float v = acc[mi][ni][r] + bv[ni];
                if (MODE == 0) {
                    if (n < 1536) v = (v > 0.f) ? (v + 1.f) : __expf(v);  // phi
                    ((ushort*)Cout)[(size_t)m * Ncols + n] = f2b(v);
                } else {
                    ((float*)Cout)[(size_t)m * Ncols + n] = v;
                }
            }
        }
    }
}

// ---------------- kv + ksum via MFMA (stride 70: conflict-free reads) ---------
__global__ __launch_bounds__(256) void k_kv(const ushort* __restrict__ QKV,
                                            float* __restrict__ kvp) {
    const int bh = blockIdx.x, s = blockIdx.y;
    const int bb = bh / 12, head = bh % 12;
    __shared__ ushort kS[64 * 70];
    __shared__ ushort vS[64 * 70];
    const int t = threadIdx.x, w = t >> 6, lane = t & 63;
    const int fr = lane & 15, fk = (lane >> 4) * 8;

    floatx4 acc[5] = {};
    const int n_ld = t >> 2, c16 = (t & 3) * 16;
    const ushort* base = QKV + (size_t)(bb * 4096 + s * 512) * 2304 + 768 + head * 64 + c16;

    for (int rr = 0; rr < 8; ++rr) {
        if (rr) __syncthreads();
        {
            const ushort* kp = base + (size_t)(rr * 64 + n_ld) * 2304;
            union { shortx8 v8; shortx2 v2[4]; } k0, k1, v0, v1;
            k0.v8 = *(const shortx8*)(kp);
            k1.v8 = *(const shortx8*)(kp + 8);
            v0.v8 = *(const shortx8*)(kp + 768);
            v1.v8 = *(const shortx8*)(kp + 776);
            ushort* kd = kS + n_ld * 70 + c16;
            ushort* vd = vS + n_ld * 70 + c16;
#pragma unroll
            for (int i = 0; i < 4; ++i) {
                *(shortx2*)(kd + 2 * i)     = k0.v2[i];
                *(shortx2*)(kd + 8 + 2 * i) = k1.v2[i];
                *(shortx2*)(vd + 2 * i)     = v0.v2[i];
                *(shortx2*)(vd + 8 + 2 * i) = v1.v2[i];
            }
        }
        __syncthreads();
#pragma unroll
        for (int kl = 0; kl < 64; kl += 32) {
            union { bf16x8 v; ushort u[8]; } bfr, afr[4];
#pragma unroll
            for (int i = 0; i < 8; ++i) {
                int n = kl + fk + i;
                bfr.u[i] = kS[n * 70 + w * 16 + fr];
#pragma unroll
                for (int mt = 0; mt < 4; ++mt)
                    afr[mt].u[i] = vS[n * 70 + mt * 16 + fr];
            }
            union { bf16x8 v; ushort u[8]; } ones;
            ushort ov = (fr == 0) ? (ushort)0x3F80 : (ushort)0;
#pragma unroll
            for (int i = 0; i < 8; ++i) ones.u[i] = ov;
#pragma unroll
            for (int mt = 0; mt < 4; ++mt)
                acc[mt] = mfma_bf16(afr[mt].v, bfr.v, acc[mt]);
            acc[4] = mfma_bf16(ones.v, bfr.v, acc[4]);
        }
    }

    float* dst = kvp + ((size_t)bh * 8 + s) * (65 * 64);
#pragma unroll
    for (int mt = 0; mt < 4; ++mt)
#pragma unroll
        for (int r = 0; r < 4; ++r)
            dst[(mt * 16 + (lane >> 4) * 4 + r) * 64 + w * 16 + fr] = acc[mt][r];
    if (lane < 16) dst[64 * 64 + w * 16 + lane] = acc[4][0];
}

// reduce 8 partials, emit bf16: kvb [48][65][64]
__global__ void k_kvred(const float* __restrict__ kvp, ushort* __restrict__ kvb) {
    int t4 = (blockIdx.x * 256 + threadIdx.x) * 4;   // 195*256*4 == 199680
    int bh = t4 / 4160, rem = t4 % 4160;
    const float* p = kvp + (size_t)bh * 8 * 4160 + rem;
    float4 sum = {0.f, 0.f, 0.f, 0.f};
    for (int i = 0; i < 8; ++i) {
        float4 a = *(const float4*)(p + (size_t)i * 4160);
        sum.x += a.x; sum.y += a.y; sum.z += a.z; sum.w += a.w;
    }
    shortx4 o;
    o[0] = (short)f2b(sum.x); o[1] = (short)f2b(sum.y);
    o[2] = (short)f2b(sum.z); o[3] = (short)f2b(sum.w);
    *(shortx4*)(kvb + t4) = o;
}

// ---------------- num + z + normed (MFMA) ----------------
__global__ __launch_bounds__(256) void k_num(const ushort* __restrict__ QKV,
                                             const ushort* __restrict__ kvb,
                                             ushort* __restrict__ normed) {
    const int bh = blockIdx.x, l0 = blockIdx.y * 128;
    const int bb = bh / 12, head = bh % 12;
    __shared__ ushort qsh[128 * 72];
    __shared__ ushort kvT[80 * 72];
    __shared__ float dnm[128];
    const int t = threadIdx.x, w = t >> 6, lane = t & 63;

    {
        const ushort* kvbb = kvb + (size_t)bh * 4160;
        int c8 = (t & 7) * 8;
        for (int r0 = (t >> 3); r0 < 65; r0 += 32)
            *(shortx8*)(kvT + r0 * 72 + c8) = *(const shortx8*)(kvbb + r0 * 64 + c8);
    }
    for (int idx = t; idx < 15 * 72; idx += 256) kvT[65 * 72 + idx] = 0;

    const ushort* qg = QKV + (size_t)(bb * 4096 + l0) * 2304 + head * 64;
    {
        int row = t >> 3, c8 = (t & 7) * 8;
#pragma unroll
        for (int i = 0; i < 4; ++i) {
            shortx8 v = *(const shortx8*)(qg + (size_t)(i * 32 + row) * 2304 + c8);
            *(shortx8*)(qsh + (i * 32 + row) * 72 + c8) = v;
        }
    }
    __syncthreads();

    const int fr = lane & 15, fk = (lane >> 4) * 8;
    floatx4 acc[2][5] = {};
#pragma unroll
    for (int kc = 0; kc < 2; ++kc) {
        bf16x8 a[2], b[5];
#pragma unroll
        for (int rt = 0; rt < 2; ++rt)
            a[rt] = *(const bf16x8*)(qsh + (w * 32 + rt * 16 + fr) * 72 + kc * 32 + fk);
#pragma unroll
        for (int nt = 0; nt < 5; ++nt)
            b[nt] = *(const bf16x8*)(kvT + (nt * 16 + fr) * 72 + kc * 32 + fk);
#pragma unroll
        for (int rt = 0; rt < 2; ++rt)
#pragma unroll
            for (int nt = 0; nt < 5; ++nt)
                acc[rt][nt] = mfma_bf16(a[rt], b[nt], acc[rt][nt]);
    }
    if (fr == 0) {
#pragma unroll
        for (int rt = 0; rt < 2; ++rt)
#pragma unroll
            for (int r = 0; r < 4; ++r)
                dnm[w * 32 + rt * 16 + (lane >> 4) * 4 + r] = acc[rt][4][r];
    }
    __syncthreads();
#pragma unroll
    for (int rt = 0; rt < 2; ++rt) {
#pragma unroll
        for (int r = 0; r < 4; ++r) {
            int ml = w * 32 + rt * 16 + (lane >> 4) * 4 + r;
            float z = 1.f / dnm[ml];
            size_t base = (size_t)(bb * 4096 + l0 + ml) * 768 + head * 64;
#pragma unroll
            for (int nt = 0; nt < 4; ++nt)
                normed[base + nt * 16 + fr] = f2b(acc[rt][nt][r] * z);
        }
    }
}

// ---------------- launch ----------------
extern "C" void kernel_launch(void* const* d_in, const int* in_sizes, int n_in,
                              void* d_out, int out_size, void* d_ws, size_t ws_size,
                              hipStream_t stream) {
    const float* x  = (const float*)d_in[0];
    const float* Wq = (const float*)d_in[1];
    const float* bq = (const float*)d_in[2];
    const float* Wk = (const float*)d_in[3];
    const float* bk = (const float*)d_in[4];
    const float* Wv = (const float*)d_in[5];
    const float* bv = (const float*)d_in[6];
    const float* Wo = (const float*)d_in[7];
    const float* bo = (const float*)d_in[8];

    char* ws = (char*)d_ws;
    ushort* Xb   = (ushort*)(ws);                 // 25,165,824 B (reused as normed)
    ushort* Wt   = (ushort*)(ws + 25165824);      //  3,538,944 B
    ushort* Wot  = (ushort*)(ws + 28704768);      //  1,179,648 B
    float*  bqkv = (float*)(ws + 29884416);       //      9,216 B
    ushort* QKV  = (ushort*)(ws + 29893632);      // 75,497,472 B
    float*  kvp  = (float*)(ws + 105391104);      //  6,389,760 B
    ushort* kvb  = (ushort*)(ws + 111780864);     //    399,360 B
    ushort* normed = Xb;

    k_prep <<<dim3(6729),     256, 0, stream>>>(x, Xb, Wq, Wk, Wv, Wo, Wt, Wot,
                                                bq, bk, bv, bqkv);
    k_gemm<0><<<dim3(64, 9),  512, 0, stream>>>(Xb, Wt, bqkv, (void*)QKV, 2304);
    k_kv   <<<dim3(48, 8),    256, 0, stream>>>(QKV, kvp);
    k_kvred<<<dim3(195),      256, 0, stream>>>(kvp, kvb);
    k_num  <<<dim3(48, 32),   256, 0, stream>>>(QKV, kvb, normed);
    k_gemm<1><<<dim3(64, 3),  512, 0, stream>>>(normed, Wot, bo, d_out, 768);
}

// Round 3
// 234.404 us; speedup vs baseline: 1.0431x; 1.0431x over previous
//
#include <hip/hip_runtime.h>
#include <cstdint>
#include <cstddef>

#define DEVI __device__ __forceinline__

typedef short    shortx8 __attribute__((ext_vector_type(8)));
typedef short    shortx4 __attribute__((ext_vector_type(4)));
typedef short    shortx2 __attribute__((ext_vector_type(2)));
typedef __bf16   bf16x8  __attribute__((ext_vector_type(8)));
typedef float    floatx4 __attribute__((ext_vector_type(4)));

DEVI unsigned short f2b(float f) {
    union { float f; unsigned u; } a; a.f = f;
    unsigned r = a.u + 0x7fffu + ((a.u >> 16) & 1u);
    return (unsigned short)(r >> 16);
}
DEVI float b2f(unsigned short u) {
    union { unsigned u; float f; } a; a.u = ((unsigned)u) << 16;
    return a.f;
}

DEVI floatx4 mfma_bf16(bf16x8 a, bf16x8 b, floatx4 c) {
    return __builtin_amdgcn_mfma_f32_16x16x32_bf16(a, b, c, 0, 0, 0);
}

DEVI void glds16(const ushort* g, ushort* l) {
    __builtin_amdgcn_global_load_lds(
        (const __attribute__((address_space(1))) void*)g,
        (__attribute__((address_space(3))) void*)l, 16, 0, 0);
}

// ---------------- fused prep: x->bf16, W transposes, bias pack ----------------
__global__ void k_prep(const float* __restrict__ x, ushort* __restrict__ xb,
                       const float* __restrict__ Wq, const float* __restrict__ Wk,
                       const float* __restrict__ Wv, const float* __restrict__ Wo,
                       ushort* __restrict__ Wt, ushort* __restrict__ Wot,
                       const float* __restrict__ bq, const float* __restrict__ bk,
                       const float* __restrict__ bv, float* __restrict__ bqkv) {
    __shared__ float tile[64][65];
    const int bid = blockIdx.x, t = threadIdx.x;
    if (bid < 6144) {                      // x -> bf16
        size_t i = ((size_t)bid * 256 + t) * 8;
        float4 v0 = *(const float4*)(x + i);
        float4 v1 = *(const float4*)(x + i + 4);
        shortx8 o;
        o[0] = (short)f2b(v0.x); o[1] = (short)f2b(v0.y);
        o[2] = (short)f2b(v0.z); o[3] = (short)f2b(v0.w);
        o[4] = (short)f2b(v1.x); o[5] = (short)f2b(v1.y);
        o[6] = (short)f2b(v1.z); o[7] = (short)f2b(v1.w);
        *(shortx8*)(xb + i) = o;
    } else if (bid < 6720) {               // W [in][out] fp32 -> [out][in] bf16
        int pid = bid - 6144;
        int zi = pid / 144, rem = pid % 144;
        const float* W = (zi == 0) ? Wq : (zi == 1) ? Wk : (zi == 2) ? Wv : Wo;
        const int i0 = (rem / 12) * 64, j0 = (rem % 12) * 64;
        const int c = t & 63, r4 = t >> 6;
        for (int rr = r4; rr < 64; rr += 4)
            tile[rr][c] = W[(size_t)(i0 + rr) * 768 + j0 + c];
        __syncthreads();
        ushort* dst = (zi < 3) ? (Wt + (size_t)(zi * 768) * 768) : Wot;
        for (int jj = r4; jj < 64; jj += 4)
            dst[(size_t)(j0 + jj) * 768 + i0 + c] = f2b(tile[c][jj]);
    } else {                               // bias pack
        int j = (bid - 6720) * 256 + t;
        if (j < 2304) {
            const float* src = (j < 768) ? bq : (j < 1536) ? bk : bv;
            bqkv[j] = src[j % 768];
        }
    }
}

// ---------------- main GEMM: BK=64, XOR chunk swizzle (round-0 structure) -----
// LDS logical As[row][k0..63]; element (r,k) at r*64 + ((k>>3)^(r&7))*8 + (k&7).
// Staging: glds16 #i covers rows +i*8..+i*8+8, lane -> (row=lane>>3, slot=lane&7),
// source column permuted per lane so coalescing (full 128B rows) is preserved.
// Register diet vs round 0: __launch_bounds__(256,4) (target total regs <=128 ->
// 4 waves/SIMD, 4 blocks/CU) + pointer arrays flattened to 2 base pointers with
// per-issue constant offsets (saves ~16 loop-invariant addr VGPRs).
template <int MODE>
__global__ __launch_bounds__(256, 4) void k_gemm(
    const ushort* __restrict__ A, const ushort* __restrict__ Bt,
    const float* __restrict__ bias, void* __restrict__ Cout, int Ncols) {
    constexpr int K = 768;
    __shared__ ushort As[128 * 64];
    __shared__ ushort Bs[128 * 64];
    const int m0 = blockIdx.x * 128;
    const int n0 = blockIdx.y * 128;
    const int tid = threadIdx.x;
    const int w = tid >> 6, lane = tid & 63;

    const int lr = lane >> 3;                    // row within 8-row slab
    const int lc = ((lane & 7) ^ lr) * 8;        // swizzled source chunk
    const ushort* aBase = A  + (size_t)(m0 + w * 32 + lr) * K + lc;
    const ushort* bBase = Bt + (size_t)(n0 + w * 32 + lr) * K + lc;
    ushort* aL = As + (w * 32) * 64;             // wave-uniform LDS bases
    ushort* bL = Bs + (w * 32) * 64;

    const int rBase = (w >> 1) * 64;
    const int nBase = (w & 1) * 64;
    const int fr = lane & 15;
    const int q4 = lane >> 4;

    floatx4 acc[4][4] = {};

    for (int k0 = 0; k0 < K; k0 += 64) {
#pragma unroll
        for (int i = 0; i < 4; ++i) glds16(aBase + i * (8 * K) + k0, aL + i * (8 * 64));
#pragma unroll
        for (int i = 0; i < 4; ++i) glds16(bBase + i * (8 * K) + k0, bL + i * (8 * 64));
        __syncthreads();
#pragma unroll
        for (int kc = 0; kc < 2; ++kc) {
            const int off = ((kc * 4 + q4) ^ (fr & 7)) * 8;
            bf16x8 af[4], bf[4];
#pragma unroll
            for (int rt = 0; rt < 4; ++rt)
                af[rt] = *(const bf16x8*)(As + (rBase + rt * 16 + fr) * 64 + off);
#pragma unroll
            for (int nt = 0; nt < 4; ++nt)
                bf[nt] = *(const bf16x8*)(Bs + (nBase + nt * 16 + fr) * 64 + off);
#pragma unroll
            for (int rt = 0; rt < 4; ++rt)
#pragma unroll
                for (int nt = 0; nt < 4; ++nt)
                    acc[rt][nt] = mfma_bf16(af[rt], bf[nt], acc[rt][nt]);
        }
        __syncthreads();
    }

#pragma unroll
    for (int rt = 0; rt < 4; ++rt) {
#pragma unroll
        for (int nt = 0; nt < 4; ++nt) {
#pragma unroll
            for (int r = 0; r < 4; ++r) {
                int m = m0 + rBase + rt * 16 + q4 * 4 + r;
                int n = n0 + nBase + nt * 16 + fr;
                float v = acc[rt][nt][r] + bias[n];
                if (MODE == 0) {
                    if (n < 1536) v = (v > 0.f) ? (v + 1.f) : __expf(v);  // phi
                    ((ushort*)Cout)[(size_t)m * Ncols + n] = f2b(v);
                } else {
                    ((float*)Cout)[(size_t)m * Ncols + n] = v;
                }
            }
        }
    }
}

// ---------------- kv + ksum via MFMA (stride 70: conflict-free reads) ---------
__global__ __launch_bounds__(256) void k_kv(const ushort* __restrict__ QKV,
                                            float* __restrict__ kvp) {
    const int bh = blockIdx.x, s = blockIdx.y;
    const int bb = bh / 12, head = bh % 12;
    __shared__ ushort kS[64 * 70];
    __shared__ ushort vS[64 * 70];
    const int t = threadIdx.x, w = t >> 6, lane = t & 63;
    const int fr = lane & 15, fk = (lane >> 4) * 8;

    floatx4 acc[5] = {};
    const int n_ld = t >> 2, c16 = (t & 3) * 16;
    const ushort* base = QKV + (size_t)(bb * 4096 + s * 512) * 2304 + 768 + head * 64 + c16;

    for (int rr = 0; rr < 8; ++rr) {
        if (rr) __syncthreads();
        {
            const ushort* kp = base + (size_t)(rr * 64 + n_ld) * 2304;
            union { shortx8 v8; shortx2 v2[4]; } k0, k1, v0, v1;
            k0.v8 = *(const shortx8*)(kp);
            k1.v8 = *(const shortx8*)(kp + 8);
            v0.v8 = *(const shortx8*)(kp + 768);
            v1.v8 = *(const shortx8*)(kp + 776);
            ushort* kd = kS + n_ld * 70 + c16;
            ushort* vd = vS + n_ld * 70 + c16;
#pragma unroll
            for (int i = 0; i < 4; ++i) {
                *(shortx2*)(kd + 2 * i)     = k0.v2[i];
                *(shortx2*)(kd + 8 + 2 * i) = k1.v2[i];
                *(shortx2*)(vd + 2 * i)     = v0.v2[i];
                *(shortx2*)(vd + 8 + 2 * i) = v1.v2[i];
            }
        }
        __syncthreads();
#pragma unroll
        for (int kl = 0; kl < 64; kl += 32) {
            union { bf16x8 v; ushort u[8]; } bfr, afr[4];
#pragma unroll
            for (int i = 0; i < 8; ++i) {
                int n = kl + fk + i;
                bfr.u[i] = kS[n * 70 + w * 16 + fr];
#pragma unroll
                for (int mt = 0; mt < 4; ++mt)
                    afr[mt].u[i] = vS[n * 70 + mt * 16 + fr];
            }
            union { bf16x8 v; ushort u[8]; } ones;
            ushort ov = (fr == 0) ? (ushort)0x3F80 : (ushort)0;
#pragma unroll
            for (int i = 0; i < 8; ++i) ones.u[i] = ov;
#pragma unroll
            for (int mt = 0; mt < 4; ++mt)
                acc[mt] = mfma_bf16(afr[mt].v, bfr.v, acc[mt]);
            acc[4] = mfma_bf16(ones.v, bfr.v, acc[4]);
        }
    }

    float* dst = kvp + ((size_t)bh * 8 + s) * (65 * 64);
#pragma unroll
    for (int mt = 0; mt < 4; ++mt)
#pragma unroll
        for (int r = 0; r < 4; ++r)
            dst[(mt * 16 + (lane >> 4) * 4 + r) * 64 + w * 16 + fr] = acc[mt][r];
    if (lane < 16) dst[64 * 64 + w * 16 + lane] = acc[4][0];
}

// reduce 8 partials, emit bf16: kvb [48][65][64]
__global__ void k_kvred(const float* __restrict__ kvp, ushort* __restrict__ kvb) {
    int t4 = (blockIdx.x * 256 + threadIdx.x) * 4;   // 195*256*4 == 199680
    int bh = t4 / 4160, rem = t4 % 4160;
    const float* p = kvp + (size_t)bh * 8 * 4160 + rem;
    float4 sum = {0.f, 0.f, 0.f, 0.f};
    for (int i = 0; i < 8; ++i) {
        float4 a = *(const float4*)(p + (size_t)i * 4160);
        sum.x += a.x; sum.y += a.y; sum.z += a.z; sum.w += a.w;
    }
    shortx4 o;
    o[0] = (short)f2b(sum.x); o[1] = (short)f2b(sum.y);
    o[2] = (short)f2b(sum.z); o[3] = (short)f2b(sum.w);
    *(shortx4*)(kvb + t4) = o;
}

// ---------------- num + z + normed (MFMA) ----------------
__global__ __launch_bounds__(256) void k_num(const ushort* __restrict__ QKV,
                                             const ushort* __restrict__ kvb,
                                             ushort* __restrict__ normed) {
    const int bh = blockIdx.x, l0 = blockIdx.y * 128;
    const int bb = bh / 12, head = bh % 12;
    __shared__ ushort qsh[128 * 72];
    __shared__ ushort kvT[80 * 72];
    __shared__ float dnm[128];
    const int t = threadIdx.x, w = t >> 6, lane = t & 63;

    {
        const ushort* kvbb = kvb + (size_t)bh * 4160;
        int c8 = (t & 7) * 8;
        for (int r0 = (t >> 3); r0 < 65; r0 += 32)
            *(shortx8*)(kvT + r0 * 72 + c8) = *(const shortx8*)(kvbb + r0 * 64 + c8);
    }
    for (int idx = t; idx < 15 * 72; idx += 256) kvT[65 * 72 + idx] = 0;

    const ushort* qg = QKV + (size_t)(bb * 4096 + l0) * 2304 + head * 64;
    {
        int row = t >> 3, c8 = (t & 7) * 8;
#pragma unroll
        for (int i = 0; i < 4; ++i) {
            shortx8 v = *(const shortx8*)(qg + (size_t)(i * 32 + row) * 2304 + c8);
            *(shortx8*)(qsh + (i * 32 + row) * 72 + c8) = v;
        }
    }
    __syncthreads();

    const int fr = lane & 15, fk = (lane >> 4) * 8;
    floatx4 acc[2][5] = {};
#pragma unroll
    for (int kc = 0; kc < 2; ++kc) {
        bf16x8 a[2], b[5];
#pragma unroll
        for (int rt = 0; rt < 2; ++rt)
            a[rt] = *(const bf16x8*)(qsh + (w * 32 + rt * 16 + fr) * 72 + kc * 32 + fk);
#pragma unroll
        for (int nt = 0; nt < 5; ++nt)
            b[nt] = *(const bf16x8*)(kvT + (nt * 16 + fr) * 72 + kc * 32 + fk);
#pragma unroll
        for (int rt = 0; rt < 2; ++rt)
#pragma unroll
            for (int nt = 0; nt < 5; ++nt)
                acc[rt][nt] = mfma_bf16(a[rt], b[nt], acc[rt][nt]);
    }
    if (fr == 0) {
#pragma unroll
        for (int rt = 0; rt < 2; ++rt)
#pragma unroll
            for (int r = 0; r < 4; ++r)
                dnm[w * 32 + rt * 16 + (lane >> 4) * 4 + r] = acc[rt][4][r];
    }
    __syncthreads();
#pragma unroll
    for (int rt = 0; rt < 2; ++rt) {
#pragma unroll
        for (int r = 0; r < 4; ++r) {
            int ml = w * 32 + rt * 16 + (lane >> 4) * 4 + r;
            float z = 1.f / dnm[ml];
            size_t base = (size_t)(bb * 4096 + l0 + ml) * 768 + head * 64;
#pragma unroll
            for (int nt = 0; nt < 4; ++nt)
                normed[base + nt * 16 + fr] = f2b(acc[rt][nt][r] * z);
        }
    }
}

// ---------------- launch ----------------
extern "C" void kernel_launch(void* const* d_in, const int* in_sizes, int n_in,
                              void* d_out, int out_size, void* d_ws, size_t ws_size,
                              hipStream_t stream) {
    const float* x  = (const float*)d_in[0];
    const float* Wq = (const float*)d_in[1];
    const float* bq = (const float*)d_in[2];
    const float* Wk = (const float*)d_in[3];
    const float* bk = (const float*)d_in[4];
    const float* Wv = (const float*)d_in[5];
    const float* bv = (const float*)d_in[6];
    const float* Wo = (const float*)d_in[7];
    const float* bo = (const float*)d_in[8];

    char* ws = (char*)d_ws;
    ushort* Xb   = (ushort*)(ws);                 // 25,165,824 B (reused as normed)
    ushort* Wt   = (ushort*)(ws + 25165824);      //  3,538,944 B
    ushort* Wot  = (ushort*)(ws + 28704768);      //  1,179,648 B
    float*  bqkv = (float*)(ws + 29884416);       //      9,216 B
    ushort* QKV  = (ushort*)(ws + 29893632);      // 75,497,472 B
    float*  kvp  = (float*)(ws + 105391104);      //  6,389,760 B
    ushort* kvb  = (ushort*)(ws + 111780864);     //    399,360 B
    ushort* normed = Xb;

    k_prep <<<dim3(6729),      256, 0, stream>>>(x, Xb, Wq, Wk, Wv, Wo, Wt, Wot,
                                                 bq, bk, bv, bqkv);
    k_gemm<0><<<dim3(128, 18), 256, 0, stream>>>(Xb, Wt, bqkv, (void*)QKV, 2304);
    k_kv   <<<dim3(48, 8),     256, 0, stream>>>(QKV, kvp);
    k_kvred<<<dim3(195),       256, 0, stream>>>(kvp, kvb);
    k_num  <<<dim3(48, 32),    256, 0, stream>>>(QKV, kvb, normed);
    k_gemm<1><<<dim3(128, 6),  256, 0, stream>>>(normed, Wot, bo, d_out, 768);
}

// Round 4
// 229.683 us; speedup vs baseline: 1.0646x; 1.0206x over previous
//
#include <hip/hip_runtime.h>
#include <cstdint>
#include <cstddef>

#define DEVI __device__ __forceinline__

typedef short    shortx8 __attribute__((ext_vector_type(8)));
typedef short    shortx4 __attribute__((ext_vector_type(4)));
typedef short    shortx2 __attribute__((ext_vector_type(2)));
typedef __bf16   bf16x8  __attribute__((ext_vector_type(8)));
typedef float    floatx4 __attribute__((ext_vector_type(4)));

DEVI unsigned short f2b(float f) {
    union { float f; unsigned u; } a; a.f = f;
    unsigned r = a.u + 0x7fffu + ((a.u >> 16) & 1u);
    return (unsigned short)(r >> 16);
}
DEVI float b2f(unsigned short u) {
    union { unsigned u; float f; } a; a.u = ((unsigned)u) << 16;
    return a.f;
}

DEVI floatx4 mfma_bf16(bf16x8 a, bf16x8 b, floatx4 c) {
    return __builtin_amdgcn_mfma_f32_16x16x32_bf16(a, b, c, 0, 0, 0);
}

DEVI void glds16(const ushort* g, ushort* l) {
    __builtin_amdgcn_global_load_lds(
        (const __attribute__((address_space(1))) void*)g,
        (__attribute__((address_space(3))) void*)l, 16, 0, 0);
}

// ---------------- fused prep: x->bf16, W transposes, bias pack ----------------
__global__ void k_prep(const float* __restrict__ x, ushort* __restrict__ xb,
                       const float* __restrict__ Wq, const float* __restrict__ Wk,
                       const float* __restrict__ Wv, const float* __restrict__ Wo,
                       ushort* __restrict__ Wt, ushort* __restrict__ Wot,
                       const float* __restrict__ bq, const float* __restrict__ bk,
                       const float* __restrict__ bv, float* __restrict__ bqkv) {
    __shared__ float tile[64][65];
    const int bid = blockIdx.x, t = threadIdx.x;
    if (bid < 6144) {                      // x -> bf16
        size_t i = ((size_t)bid * 256 + t) * 8;
        float4 v0 = *(const float4*)(x + i);
        float4 v1 = *(const float4*)(x + i + 4);
        shortx8 o;
        o[0] = (short)f2b(v0.x); o[1] = (short)f2b(v0.y);
        o[2] = (short)f2b(v0.z); o[3] = (short)f2b(v0.w);
        o[4] = (short)f2b(v1.x); o[5] = (short)f2b(v1.y);
        o[6] = (short)f2b(v1.z); o[7] = (short)f2b(v1.w);
        *(shortx8*)(xb + i) = o;
    } else if (bid < 6720) {               // W [in][out] fp32 -> [out][in] bf16
        int pid = bid - 6144;
        int zi = pid / 144, rem = pid % 144;
        const float* W = (zi == 0) ? Wq : (zi == 1) ? Wk : (zi == 2) ? Wv : Wo;
        const int i0 = (rem / 12) * 64, j0 = (rem % 12) * 64;
        const int c = t & 63, r4 = t >> 6;
        for (int rr = r4; rr < 64; rr += 4)
            tile[rr][c] = W[(size_t)(i0 + rr) * 768 + j0 + c];
        __syncthreads();
        ushort* dst = (zi < 3) ? (Wt + (size_t)(zi * 768) * 768) : Wot;
        for (int jj = r4; jj < 64; jj += 4)
            dst[(size_t)(j0 + jj) * 768 + i0 + c] = f2b(tile[c][jj]);
    } else {                               // bias pack
        int j = (bid - 6720) * 256 + t;
        if (j < 2304) {
            const float* src = (j < 768) ? bq : (j < 1536) ? bk : bv;
            bqkv[j] = src[j % 768];
        }
    }
}

// ---------------- main GEMM: BK=64, XOR chunk swizzle + locality swizzle ------
// LDS logical As[row][k0..63]; element (r,k) at r*64 + ((k>>3)^(r&7))*8 + (k&7).
// Staging: glds16 #i covers rows +i*8..+i*8+8, lane -> (row=lane>>3, slot=lane&7),
// source column permuted per lane so coalescing (full 128B rows) is preserved.
// Block-index swizzle (NEW, round 4): two bijective layers on the linear
// dispatch id (x-fastest order):
//   1. XCD chunking (m204): wg = (lin&7)*(NWG/8) + (lin>>3) -> each XCD's L2
//      holds a stable contiguous slice of logical tiles.
//   2. Super-tile traversal: logical order = band of 8 m-blocks (fast) x all
//      n-blocks (slow). 8 A-panels (1.6 MB) stay L2-hot while 196 KB B panels
//      stream -> L3-level A re-reads drop from x18 (gemm<0>) / x6 (gemm<1>)
//      to ~x1.
template <int MODE>
__global__ __launch_bounds__(256, 4) void k_gemm(
    const ushort* __restrict__ A, const ushort* __restrict__ Bt,
    const float* __restrict__ bias, void* __restrict__ Cout, int Ncols) {
    constexpr int K = 768;
    constexpr int GY = (MODE == 0) ? 18 : 6;   // grid.y (must match launch)
    constexpr int NWG = 128 * GY;
    __shared__ ushort As[128 * 64];
    __shared__ ushort Bs[128 * 64];

    const int lin  = blockIdx.y * 128 + blockIdx.x;       // dispatch order
    const int wg   = (lin & 7) * (NWG / 8) + (lin >> 3);  // XCD-contiguous
    const int band = wg / (8 * GY);                       // super-row of 8 m-blocks
    const int rem  = wg % (8 * GY);
    const int m0 = (band * 8 + (rem & 7)) * 128;
    const int n0 = (rem >> 3) * 128;

    const int tid = threadIdx.x;
    const int w = tid >> 6, lane = tid & 63;

    const int lr = lane >> 3;                    // row within 8-row slab
    const int lc = ((lane & 7) ^ lr) * 8;        // swizzled source chunk
    const ushort* aBase = A  + (size_t)(m0 + w * 32 + lr) * K + lc;
    const ushort* bBase = Bt + (size_t)(n0 + w * 32 + lr) * K + lc;
    ushort* aL = As + (w * 32) * 64;             // wave-uniform LDS bases
    ushort* bL = Bs + (w * 32) * 64;

    const int rBase = (w >> 1) * 64;
    const int nBase = (w & 1) * 64;
    const int fr = lane & 15;
    const int q4 = lane >> 4;

    floatx4 acc[4][4] = {};

    for (int k0 = 0; k0 < K; k0 += 64) {
#pragma unroll
        for (int i = 0; i < 4; ++i) glds16(aBase + i * (8 * K) + k0, aL + i * (8 * 64));
#pragma unroll
        for (int i = 0; i < 4; ++i) glds16(bBase + i * (8 * K) + k0, bL + i * (8 * 64));
        __syncthreads();
#pragma unroll
        for (int kc = 0; kc < 2; ++kc) {
            const int off = ((kc * 4 + q4) ^ (fr & 7)) * 8;
            bf16x8 af[4], bf[4];
#pragma unroll
            for (int rt = 0; rt < 4; ++rt)
                af[rt] = *(const bf16x8*)(As + (rBase + rt * 16 + fr) * 64 + off);
#pragma unroll
            for (int nt = 0; nt < 4; ++nt)
                bf[nt] = *(const bf16x8*)(Bs + (nBase + nt * 16 + fr) * 64 + off);
#pragma unroll
            for (int rt = 0; rt < 4; ++rt)
#pragma unroll
                for (int nt = 0; nt < 4; ++nt)
                    acc[rt][nt] = mfma_bf16(af[rt], bf[nt], acc[rt][nt]);
        }
        __syncthreads();
    }

#pragma unroll
    for (int rt = 0; rt < 4; ++rt) {
#pragma unroll
        for (int nt = 0; nt < 4; ++nt) {
#pragma unroll
            for (int r = 0; r < 4; ++r) {
                int m = m0 + rBase + rt * 16 + q4 * 4 + r;
                int n = n0 + nBase + nt * 16 + fr;
                float v = acc[rt][nt][r] + bias[n];
                if (MODE == 0) {
                    if (n < 1536) v = (v > 0.f) ? (v + 1.f) : __expf(v);  // phi
                    ((ushort*)Cout)[(size_t)m * Ncols + n] = f2b(v);
                } else {
                    ((float*)Cout)[(size_t)m * Ncols + n] = v;
                }
            }
        }
    }
}

// ---------------- kv + ksum via MFMA (stride 70: conflict-free reads) ---------
__global__ __launch_bounds__(256) void k_kv(const ushort* __restrict__ QKV,
                                            float* __restrict__ kvp) {
    const int bh = blockIdx.x, s = blockIdx.y;
    const int bb = bh / 12, head = bh % 12;
    __shared__ ushort kS[64 * 70];
    __shared__ ushort vS[64 * 70];
    const int t = threadIdx.x, w = t >> 6, lane = t & 63;
    const int fr = lane & 15, fk = (lane >> 4) * 8;

    floatx4 acc[5] = {};
    const int n_ld = t >> 2, c16 = (t & 3) * 16;
    const ushort* base = QKV + (size_t)(bb * 4096 + s * 512) * 2304 + 768 + head * 64 + c16;

    for (int rr = 0; rr < 8; ++rr) {
        if (rr) __syncthreads();
        {
            const ushort* kp = base + (size_t)(rr * 64 + n_ld) * 2304;
            union { shortx8 v8; shortx2 v2[4]; } k0, k1, v0, v1;
            k0.v8 = *(const shortx8*)(kp);
            k1.v8 = *(const shortx8*)(kp + 8);
            v0.v8 = *(const shortx8*)(kp + 768);
            v1.v8 = *(const shortx8*)(kp + 776);
            ushort* kd = kS + n_ld * 70 + c16;
            ushort* vd = vS + n_ld * 70 + c16;
#pragma unroll
            for (int i = 0; i < 4; ++i) {
                *(shortx2*)(kd + 2 * i)     = k0.v2[i];
                *(shortx2*)(kd + 8 + 2 * i) = k1.v2[i];
                *(shortx2*)(vd + 2 * i)     = v0.v2[i];
                *(shortx2*)(vd + 8 + 2 * i) = v1.v2[i];
            }
        }
        __syncthreads();
#pragma unroll
        for (int kl = 0; kl < 64; kl += 32) {
            union { bf16x8 v; ushort u[8]; } bfr, afr[4];
#pragma unroll
            for (int i = 0; i < 8; ++i) {
                int n = kl + fk + i;
                bfr.u[i] = kS[n * 70 + w * 16 + fr];
#pragma unroll
                for (int mt = 0; mt < 4; ++mt)
                    afr[mt].u[i] = vS[n * 70 + mt * 16 + fr];
            }
            union { bf16x8 v; ushort u[8]; } ones;
            ushort ov = (fr == 0) ? (ushort)0x3F80 : (ushort)0;
#pragma unroll
            for (int i = 0; i < 8; ++i) ones.u[i] = ov;
#pragma unroll
            for (int mt = 0; mt < 4; ++mt)
                acc[mt] = mfma_bf16(afr[mt].v, bfr.v, acc[mt]);
            acc[4] = mfma_bf16(ones.v, bfr.v, acc[4]);
        }
    }

    float* dst = kvp + ((size_t)bh * 8 + s) * (65 * 64);
#pragma unroll
    for (int mt = 0; mt < 4; ++mt)
#pragma unroll
        for (int r = 0; r < 4; ++r)
            dst[(mt * 16 + (lane >> 4) * 4 + r) * 64 + w * 16 + fr] = acc[mt][r];
    if (lane < 16) dst[64 * 64 + w * 16 + lane] = acc[4][0];
}

// reduce 8 partials, emit bf16: kvb [48][65][64]
__global__ void k_kvred(const float* __restrict__ kvp, ushort* __restrict__ kvb) {
    int t4 = (blockIdx.x * 256 + threadIdx.x) * 4;   // 195*256*4 == 199680
    int bh = t4 / 4160, rem = t4 % 4160;
    const float* p = kvp + (size_t)bh * 8 * 4160 + rem;
    float4 sum = {0.f, 0.f, 0.f, 0.f};
    for (int i = 0; i < 8; ++i) {
        float4 a = *(const float4*)(p + (size_t)i * 4160);
        sum.x += a.x; sum.y += a.y; sum.z += a.z; sum.w += a.w;
    }
    shortx4 o;
    o[0] = (short)f2b(sum.x); o[1] = (short)f2b(sum.y);
    o[2] = (short)f2b(sum.z); o[3] = (short)f2b(sum.w);
    *(shortx4*)(kvb + t4) = o;
}

// ---------------- num + z + normed (MFMA) ----------------
__global__ __launch_bounds__(256) void k_num(const ushort* __restrict__ QKV,
                                             const ushort* __restrict__ kvb,
                                             ushort* __restrict__ normed) {
    const int bh = blockIdx.x, l0 = blockIdx.y * 128;
    const int bb = bh / 12, head = bh % 12;
    __shared__ ushort qsh[128 * 72];
    __shared__ ushort kvT[80 * 72];
    __shared__ float dnm[128];
    const int t = threadIdx.x, w = t >> 6, lane = t & 63;

    {
        const ushort* kvbb = kvb + (size_t)bh * 4160;
        int c8 = (t & 7) * 8;
        for (int r0 = (t >> 3); r0 < 65; r0 += 32)
            *(shortx8*)(kvT + r0 * 72 + c8) = *(const shortx8*)(kvbb + r0 * 64 + c8);
    }
    for (int idx = t; idx < 15 * 72; idx += 256) kvT[65 * 72 + idx] = 0;

    const ushort* qg = QKV + (size_t)(bb * 4096 + l0) * 2304 + head * 64;
    {
        int row = t >> 3, c8 = (t & 7) * 8;
#pragma unroll
        for (int i = 0; i < 4; ++i) {
            shortx8 v = *(const shortx8*)(qg + (size_t)(i * 32 + row) * 2304 + c8);
            *(shortx8*)(qsh + (i * 32 + row) * 72 + c8) = v;
        }
    }
    __syncthreads();

    const int fr = lane & 15, fk = (lane >> 4) * 8;
    floatx4 acc[2][5] = {};
#pragma unroll
    for (int kc = 0; kc < 2; ++kc) {
        bf16x8 a[2], b[5];
#pragma unroll
        for (int rt = 0; rt < 2; ++rt)
            a[rt] = *(const bf16x8*)(qsh + (w * 32 + rt * 16 + fr) * 72 + kc * 32 + fk);
#pragma unroll
        for (int nt = 0; nt < 5; ++nt)
            b[nt] = *(const bf16x8*)(kvT + (nt * 16 + fr) * 72 + kc * 32 + fk);
#pragma unroll
        for (int rt = 0; rt < 2; ++rt)
#pragma unroll
            for (int nt = 0; nt < 5; ++nt)
                acc[rt][nt] = mfma_bf16(a[rt], b[nt], acc[rt][nt]);
    }
    if (fr == 0) {
#pragma unroll
        for (int rt = 0; rt < 2; ++rt)
#pragma unroll
            for (int r = 0; r < 4; ++r)
                dnm[w * 32 + rt * 16 + (lane >> 4) * 4 + r] = acc[rt][4][r];
    }
    __syncthreads();
#pragma unroll
    for (int rt = 0; rt < 2; ++rt) {
#pragma unroll
        for (int r = 0; r < 4; ++r) {
            int ml = w * 32 + rt * 16 + (lane >> 4) * 4 + r;
            float z = 1.f / dnm[ml];
            size_t base = (size_t)(bb * 4096 + l0 + ml) * 768 + head * 64;
#pragma unroll
            for (int nt = 0; nt < 4; ++nt)
                normed[base + nt * 16 + fr] = f2b(acc[rt][nt][r] * z);
        }
    }
}

// ---------------- launch ----------------
extern "C" void kernel_launch(void* const* d_in, const int* in_sizes, int n_in,
                              void* d_out, int out_size, void* d_ws, size_t ws_size,
                              hipStream_t stream) {
    const float* x  = (const float*)d_in[0];
    const float* Wq = (const float*)d_in[1];
    const float* bq = (const float*)d_in[2];
    const float* Wk = (const float*)d_in[3];
    const float* bk = (const float*)d_in[4];
    const float* Wv = (const float*)d_in[5];
    const float* bv = (const float*)d_in[6];
    const float* Wo = (const float*)d_in[7];
    const float* bo = (const float*)d_in[8];

    char* ws = (char*)d_ws;
    ushort* Xb   = (ushort*)(ws);                 // 25,165,824 B (reused as normed)
    ushort* Wt   = (ushort*)(ws + 25165824);      //  3,538,944 B
    ushort* Wot  = (ushort*)(ws + 28704768);      //  1,179,648 B
    float*  bqkv = (float*)(ws + 29884416);       //      9,216 B
    ushort* QKV  = (ushort*)(ws + 29893632);      // 75,497,472 B
    float*  kvp  = (float*)(ws + 105391104);      //  6,389,760 B
    ushort* kvb  = (ushort*)(ws + 111780864);     //    399,360 B
    ushort* normed = Xb;

    k_prep <<<dim3(6729),      256, 0, stream>>>(x, Xb, Wq, Wk, Wv, Wo, Wt, Wot,
                                                 bq, bk, bv, bqkv);
    k_gemm<0><<<dim3(128, 18), 256, 0, stream>>>(Xb, Wt, bqkv, (void*)QKV, 2304);
    k_kv   <<<dim3(48, 8),     256, 0, stream>>>(QKV, kvp);
    k_kvred<<<dim3(195),       256, 0, stream>>>(kvp, kvb);
    k_num  <<<dim3(48, 32),    256, 0, stream>>>(QKV, kvb, normed);
    k_gemm<1><<<dim3(128, 6),  256, 0, stream>>>(normed, Wot, bo, d_out, 768);
}